// Round 21
// baseline (138.360 us; speedup 1.0000x reference)
//
#include <hip/hip_runtime.h>
#include <cfloat>
#include <cmath>

#define M     16384
#define K     4096
#define E     64
#define TOPK  8
#define GAP_THRESH 1e-4f

#define NCH   (K / 32)          // 128 chunks of k32 (full K per block)
#define RCAP  2048              // max rescued rows
#define FKS   8                 // rescue K-split

typedef __attribute__((ext_vector_type(8))) short bf16x8;
typedef __attribute__((ext_vector_type(4))) float f32x4;

// ws layout: [Whf 512K][Wlf 512K][count 256B][list 64KB][dsum 8MB]

__device__ __forceinline__ short f2bf(float f) {           // RNE fp32->bf16
    unsigned u = __builtin_bit_cast(unsigned, f);
    u += 0x7FFFu + ((u >> 16) & 1u);
    return (short)(u >> 16);
}
__device__ __forceinline__ float bf2f(short h) {           // exact widen
    unsigned u = ((unsigned)(unsigned short)h) << 16;
    return __builtin_bit_cast(float, u);
}

// ---------------------------------------------------------------------------
// prep (r17-r20 byte-identical): Whf/Wlf in MFMA fragment order; zero count.
// ---------------------------------------------------------------------------
__global__ __launch_bounds__(256) void prep_kernel(const float* __restrict__ W,
                                                   short* __restrict__ Whf,
                                                   short* __restrict__ Wlf,
                                                   int* __restrict__ count) {
    int t = blockIdx.x * 256 + threadIdx.x;   // t = e*4096 + k
    float w = W[t];
    short h = f2bf(w);
    short lo = f2bf(w - bf2f(h));
    int e = t >> 12, k = t & 4095;
    int gc = k >> 5, kk = k & 31;
    size_t fidx = (((size_t)gc * 4 + (e >> 4)) * 64 + (kk >> 3) * 16 + (e & 15)) * 8
                  + (kk & 7);
    Whf[fidx] = h;
    Wlf[fidx] = lo;
    if (t == 0) *count = 0;
}

// ---------------------------------------------------------------------------
// MFMA gate, r21: SPLIT=1 + FUSED epilogue.  Main loop is the r12-proven
// 2-deep register pipeline (just NCH 32->128, k0=0).  grid 256 = 1 block/CU,
// 4 waves x 16 rows x 64 experts.  Then acc -> 16KB LDS llog (r10-verified
// D-layout transcription) and each wave runs the proven ballot top-9 +
// sparse softmax + flag epilogue on its OWN 16 rows -- no barrier, no part
// buffer (kills 32MB of traffic), no reduce kernel, one fewer launch.
// ---------------------------------------------------------------------------
struct XW {
    float4 xa, xb;
    bf16x8 h0, h1, h2, h3, l0, l1, l2, l3;
};

__device__ __forceinline__ void load_set(XW& s, const float* gx,
                                         const short* ph, const short* pl, int cc) {
    const int ko = cc * 32;
    s.xa = *reinterpret_cast<const float4*>(gx + ko);
    s.xb = *reinterpret_cast<const float4*>(gx + ko + 4);
    const short* bh = ph + (size_t)cc * 2048;
    const short* bl = pl + (size_t)cc * 2048;
    s.h0 = *reinterpret_cast<const bf16x8*>(bh);
    s.h1 = *reinterpret_cast<const bf16x8*>(bh + 512);
    s.h2 = *reinterpret_cast<const bf16x8*>(bh + 1024);
    s.h3 = *reinterpret_cast<const bf16x8*>(bh + 1536);
    s.l0 = *reinterpret_cast<const bf16x8*>(bl);
    s.l1 = *reinterpret_cast<const bf16x8*>(bl + 512);
    s.l2 = *reinterpret_cast<const bf16x8*>(bl + 1024);
    s.l3 = *reinterpret_cast<const bf16x8*>(bl + 1536);
}

__device__ __forceinline__ void compute_set(const XW& s, f32x4 acc[4]) {
    float vv[8] = {s.xa.x, s.xa.y, s.xa.z, s.xa.w, s.xb.x, s.xb.y, s.xb.z, s.xb.w};
    bf16x8 ah, al;
#pragma unroll
    for (int j = 0; j < 8; ++j) {
        short hh = f2bf(vv[j]);
        ah[j] = hh;
        al[j] = f2bf(vv[j] - bf2f(hh));
    }
    acc[0] = __builtin_amdgcn_mfma_f32_16x16x32_bf16(ah, s.h0, acc[0], 0, 0, 0);
    acc[0] = __builtin_amdgcn_mfma_f32_16x16x32_bf16(ah, s.l0, acc[0], 0, 0, 0);
    acc[0] = __builtin_amdgcn_mfma_f32_16x16x32_bf16(al, s.h0, acc[0], 0, 0, 0);
    acc[1] = __builtin_amdgcn_mfma_f32_16x16x32_bf16(ah, s.h1, acc[1], 0, 0, 0);
    acc[1] = __builtin_amdgcn_mfma_f32_16x16x32_bf16(ah, s.l1, acc[1], 0, 0, 0);
    acc[1] = __builtin_amdgcn_mfma_f32_16x16x32_bf16(al, s.h1, acc[1], 0, 0, 0);
    acc[2] = __builtin_amdgcn_mfma_f32_16x16x32_bf16(ah, s.h2, acc[2], 0, 0, 0);
    acc[2] = __builtin_amdgcn_mfma_f32_16x16x32_bf16(ah, s.l2, acc[2], 0, 0, 0);
    acc[2] = __builtin_amdgcn_mfma_f32_16x16x32_bf16(al, s.h2, acc[2], 0, 0, 0);
    acc[3] = __builtin_amdgcn_mfma_f32_16x16x32_bf16(ah, s.h3, acc[3], 0, 0, 0);
    acc[3] = __builtin_amdgcn_mfma_f32_16x16x32_bf16(ah, s.l3, acc[3], 0, 0, 0);
    acc[3] = __builtin_amdgcn_mfma_f32_16x16x32_bf16(al, s.h3, acc[3], 0, 0, 0);
}

__global__ __launch_bounds__(256) void gate_kernel(
    const float* __restrict__ x,
    const short* __restrict__ Whf,
    const short* __restrict__ Wlf,
    const float* __restrict__ b,
    float* __restrict__ outp,
    float* __restrict__ outi,
    int*   __restrict__ count,
    int*   __restrict__ list)
{
    __shared__ float llog[64 * E];       // 16 KB logit tile

    const int t  = threadIdx.x;
    const int l  = t & 63;
    const int wv = t >> 6;
    const int row0 = blockIdx.x * 64 + wv * 16;

    const int kg   = l >> 4;                          // 0..3 k-granule
    const int xrow = row0 + (l & 15);

    const float* gx = x + (size_t)xrow * K + kg * 8;
    const short* ph = Whf + (size_t)l * 8;
    const short* pl = Wlf + (size_t)l * 8;

    f32x4 acc[4] = {{0,0,0,0},{0,0,0,0},{0,0,0,0},{0,0,0,0}};

    XW A, B;
    load_set(A, gx, ph, pl, 0);
    for (int c = 0; c < NCH; c += 2) {
        load_set(B, gx, ph, pl, c + 1);
        compute_set(A, acc);
        if (c + 2 < NCH) load_set(A, gx, ph, pl, c + 2);
        compute_set(B, acc);
    }

    // D layout (verified r10-r20): row = (l>>4)*4 + r, col = l&15
#pragma unroll
    for (int et = 0; et < 4; ++et)
#pragma unroll
        for (int r = 0; r < 4; ++r)
            llog[((size_t)wv * 16 + (l >> 4) * 4 + r) * E + et * 16 + (l & 15)]
                = acc[et][r];
    // no barrier: each wave reads only its own 16 rows (within-wave lgkmcnt)

    const float bv = b[l];
    for (int rr = 0; rr < 16; ++rr) {
        const int rloc = wv * 16 + rr;
        const int row  = blockIdx.x * 64 + rloc;
        const float orig = llog[rloc * E + l] + bv;

        // proven fp32 top-9 ballot epilogue (r3-r20)
        float cur = orig;
        float vals[9];
        float myidxf = 0.0f;
        bool  sel = false;

#pragma unroll
        for (int i = 0; i < 9; ++i) {
            float m = cur;
#pragma unroll
            for (int off = 32; off > 0; off >>= 1)
                m = fmaxf(m, __shfl_xor(m, off, 64));
            unsigned long long msk = __ballot(cur == m);
            int il = __ffsll((long long)msk) - 1;
            vals[i] = m;
            if (l == il) { cur = -FLT_MAX; if (i < TOPK) sel = true; }
            if (i < TOPK && l == i) myidxf = (float)il;
        }

        float ssum = 0.0f;
#pragma unroll
        for (int i = 0; i < TOPK; ++i) ssum += expf(vals[i] - vals[0]);
        float p = sel ? (expf(orig - vals[0]) / ssum) : 0.0f;

        outp[(size_t)row * E + l] = p;
        if (l < TOPK) outi[(size_t)row * TOPK + l] = myidxf;

        float mingap = FLT_MAX;
#pragma unroll
        for (int i = 0; i < 8; ++i) mingap = fminf(mingap, vals[i] - vals[i + 1]);
        if (l == 0 && mingap < GAP_THRESH) {
            int pos = atomicAdd(count, 1);
            if (pos < M) list[pos] = row;
        }
    }
}

// ---------------------------------------------------------------------------
// fix1 (r20 byte-identical): fp64 partial dots, K-split 8 across blocks.
// ---------------------------------------------------------------------------
__global__ __launch_bounds__(256) void fix1_kernel(
    const float* __restrict__ x,
    const float* __restrict__ W,
    double* __restrict__ dsum,          // [RCAP][FKS][E]
    const int* __restrict__ count,
    const int* __restrict__ list)
{
    __shared__ float xsl[512];
    const int t   = threadIdx.x;
    const int l   = t & 63;
    const int wv  = t >> 6;
    const int tot = min(*count, RCAP) * FKS;

    for (int p = blockIdx.x; p < tot; p += gridDim.x) {
        const int i   = p >> 3;
        const int ks  = p & 7;
        const int row = list[i];
        const int k0  = ks << 9;

        if (t < 128)
            reinterpret_cast<float4*>(xsl)[t] =
                reinterpret_cast<const float4*>(x + (size_t)row * K + k0)[t];
        __syncthreads();

        const float4* xs4 = reinterpret_cast<const float4*>(xsl);

#pragma unroll
        for (int g = 0; g < 2; ++g) {
            const int e0 = wv * 16 + g * 8;
            float4 w0[8], w1[8];
#pragma unroll
            for (int e8 = 0; e8 < 8; ++e8) {
                const float4* wp = reinterpret_cast<const float4*>(
                    W + (size_t)(e0 + e8) * K + k0);
                w0[e8] = wp[l];
                w1[e8] = wp[l + 64];
            }
            float4 xv0 = xs4[l];
            float4 xv1 = xs4[l + 64];

            double s[8];
#pragma unroll
            for (int e8 = 0; e8 < 8; ++e8) {
                double a = 0.0;
                a = fma((double)xv0.x, (double)w0[e8].x, a);
                a = fma((double)xv0.y, (double)w0[e8].y, a);
                a = fma((double)xv0.z, (double)w0[e8].z, a);
                a = fma((double)xv0.w, (double)w0[e8].w, a);
                a = fma((double)xv1.x, (double)w1[e8].x, a);
                a = fma((double)xv1.y, (double)w1[e8].y, a);
                a = fma((double)xv1.z, (double)w1[e8].z, a);
                a = fma((double)xv1.w, (double)w1[e8].w, a);
                s[e8] = a;
            }

#pragma unroll
            for (int e8 = 0; e8 < 8; ++e8) {
                double v = s[e8];
#pragma unroll
                for (int off = 32; off > 0; off >>= 1)
                    v += __shfl_xor(v, off, 64);
                if (l == 0)
                    dsum[((size_t)i * FKS + ks) * E + e0 + e8] = v;
            }
        }
        __syncthreads();
    }
}

// ---------------------------------------------------------------------------
// fix2 (r20 byte-identical): combine partials + proven fp64 ballot epilogue.
// ---------------------------------------------------------------------------
__global__ __launch_bounds__(64) void fix2_kernel(
    const double* __restrict__ dsum,
    const float*  __restrict__ b,
    float* __restrict__ outp,
    float* __restrict__ outi,
    const int* __restrict__ count,
    const int* __restrict__ list)
{
    const int l   = threadIdx.x;
    const int cnt = min(*count, RCAP);

    for (int i = blockIdx.x; i < cnt; i += gridDim.x) {
        const int row = list[i];

        double orig = (double)b[l];
#pragma unroll
        for (int ks = 0; ks < FKS; ++ks)
            orig += dsum[((size_t)i * FKS + ks) * E + l];

        double cur = orig;
        double vals[TOPK];
        float  myidxf = 0.0f;
        bool   sel = false;

#pragma unroll
        for (int tt = 0; tt < TOPK; ++tt) {
            double m = cur;
#pragma unroll
            for (int off = 32; off > 0; off >>= 1) {
                double o = __shfl_xor(m, off, 64);
                m = fmax(m, o);
            }
            unsigned long long msk = __ballot(cur == m);
            int il = __ffsll((long long)msk) - 1;
            vals[tt] = m;
            if (l == il) { cur = -DBL_MAX; sel = true; }
            if (l == tt)  myidxf = (float)il;
        }

        double ssum = 0.0;
#pragma unroll
        for (int tt = 0; tt < TOPK; ++tt) ssum += exp(vals[tt] - vals[0]);
        float p = sel ? (float)(exp(orig - vals[0]) / ssum) : 0.0f;

        outp[(size_t)row * E + l] = p;
        if (l < TOPK) outi[(size_t)row * TOPK + l] = myidxf;
    }
}

// ---------------------------------------------------------------------------
// Fallback (tiny ws): per-thread-row full fp64 from f32 W.  Correct, slow.
// ---------------------------------------------------------------------------
__global__ __launch_bounds__(64) void fallback_kernel(
    const float* __restrict__ x,
    const float* __restrict__ W,
    const float* __restrict__ b,
    float* __restrict__ outp,
    float* __restrict__ outi)
{
    const int row = blockIdx.x * 64 + threadIdx.x;
    double lg[64];
#pragma unroll
    for (int e = 0; e < 64; ++e) lg[e] = (double)b[e];
    const float* xr = x + (size_t)row * K;
    for (int k = 0; k < K; k += 4) {
        float4 xa = *reinterpret_cast<const float4*>(xr + k);
        double xd[4] = {(double)xa.x, (double)xa.y, (double)xa.z, (double)xa.w};
#pragma unroll
        for (int e = 0; e < 64; ++e) {
            const float* wp = W + (size_t)e * K + k;
            double a = lg[e];
#pragma unroll
            for (int j = 0; j < 4; ++j) a = fma(xd[j], (double)wp[j], a);
            lg[e] = a;
        }
    }
    unsigned long long selm = 0ull;
    double vals[TOPK]; int idx[TOPK];
#pragma unroll
    for (int i = 0; i < TOPK; ++i) {
        double m = -DBL_MAX; int mi = 0;
#pragma unroll
        for (int e = 0; e < 64; ++e) {
            bool gt = !((selm >> e) & 1ull) && (lg[e] > m);
            m = gt ? lg[e] : m; mi = gt ? e : mi;
        }
        vals[i] = m; idx[i] = mi; selm |= (1ull << mi);
    }
    double ssum = 0.0;
#pragma unroll
    for (int i = 0; i < TOPK; ++i) ssum += exp(vals[i] - vals[0]);
    double inv = 1.0 / ssum;
#pragma unroll
    for (int e = 0; e < 64; ++e)
        outp[(size_t)row * E + e] =
            ((selm >> e) & 1ull) ? (float)(exp(lg[e] - vals[0]) * inv) : 0.0f;
#pragma unroll
    for (int i = 0; i < TOPK; ++i)
        outi[(size_t)row * TOPK + i] = (float)idx[i];
}

// ---------------------------------------------------------------------------
extern "C" void kernel_launch(void* const* d_in, const int* in_sizes, int n_in,
                              void* d_out, int out_size, void* d_ws, size_t ws_size,
                              hipStream_t stream) {
    (void)in_sizes; (void)n_in; (void)out_size;
    const float* x = (const float*)d_in[0];
    const float* W = (const float*)d_in[1];
    const float* b = (const float*)d_in[2];

    float* outp = (float*)d_out;
    float* outi = outp + (size_t)M * E;

    const size_t wh_off   = 0;
    const size_t wl_off   = wh_off + sizeof(short) * (size_t)E * K;   // +512 KB
    const size_t cnt_off  = wl_off + sizeof(short) * (size_t)E * K;   // +512 KB
    const size_t list_off = cnt_off + 256;
    const size_t dsum_off = list_off + (size_t)M * sizeof(int);
    const size_t need     = dsum_off + (size_t)RCAP * FKS * E * sizeof(double);

    if (ws_size >= need) {
        short*  Whf  = (short*)((char*)d_ws + wh_off);
        short*  Wlf  = (short*)((char*)d_ws + wl_off);
        int*    cnt  = (int*)((char*)d_ws + cnt_off);
        int*    list = (int*)((char*)d_ws + list_off);
        double* dsum = (double*)((char*)d_ws + dsum_off);

        prep_kernel<<<(E * K) / 256, 256, 0, stream>>>(W, Whf, Wlf, cnt);
        gate_kernel<<<M / 64, 256, 0, stream>>>(x, Whf, Wlf, b, outp, outi, cnt, list);
        fix1_kernel<<<4096, 256, 0, stream>>>(x, W, dsum, cnt, list);
        fix2_kernel<<<1024, 64, 0, stream>>>(dsum, b, outp, outi, cnt, list);
    } else {
        fallback_kernel<<<M / 64, 64, 0, stream>>>(x, W, b, outp, outi);
    }
}